// Round 2
// baseline (236.037 us; speedup 1.0000x reference)
//
#include <hip/hip_runtime.h>
#include <hip/hip_bf16.h>
#include <cstdint>
#include <cstddef>

// ---------------------------------------------------------------------------
// TriangleTensorNetwork, restructured:
//   T[s,r,o] = sum_{x,y,z} cs[s,y,z] cr[x,r,z] co[x,y,o]   (batch-independent)
//   out[b]   = sum_s p1[b,s] * sum_{r,o} p2[b,r] p3[b,o] T[s,r,o]
// Stages (all bf16 MFMA, f32 accumulate):
//   k_prep : cast/transpose weights to NT ([n][k], k-contiguous) bf16 layouts
//   k_proj : p1 = in1@proj_s ; h1 = relu(in2@W21^T+b21) ; p3 = in3@proj_o
//   k_mlp  : h2 = relu(h1@W22^T+b22); h3 = h2@W23^T+b23; p2 = h3@proj_r
//   k_F    : F[(x,r),(s,y)] = sum_z cr[x,r,z] cs[s,y,z]       (4096x4096, K=64)
//   k_T    : T_s[r,o] = sum_{x,y} F[x,r,s,y] co[x,y,o]  -> Tts[s][(r,o)]
//   k_main : C[b,s] = sum_{ro} (p2[b,r] p3[b,o]) Tts[s,ro]; out[b]=dot(p1[b],C[b])
// ---------------------------------------------------------------------------

typedef __attribute__((ext_vector_type(8))) short short8;
typedef __attribute__((ext_vector_type(4))) float f32x4;

#define DEV static __device__ __forceinline__

constexpr int NB = 16384;   // batch
constexpr int ND = 512;     // outer dim

DEV unsigned short f2bf(float f) {
    union { float f; unsigned u; } v; v.f = f;
    unsigned r = v.u + 0x7FFFu + ((v.u >> 16) & 1u);   // RNE
    return (unsigned short)(r >> 16);
}
DEV float bf2f(unsigned short h) {
    union { unsigned u; float f; } v; v.u = ((unsigned)h) << 16;
    return v.f;
}
// XOR swizzle on byte addr bits 4..6 keyed by row (rows are >=128B apart)
DEV unsigned swz(unsigned byte_addr, int row) {
    return byte_addr ^ ((unsigned)(row & 7) << 4);
}

// ---------------------------------------------------------------------------
// K0: weight prep (bf16 casts, transposes into [n][k] k-contiguous layouts)
// ---------------------------------------------------------------------------
__global__ void k_prep(const float* __restrict__ proj_s, const float* __restrict__ proj_r,
                       const float* __restrict__ proj_o, const float* __restrict__ cube_s,
                       const float* __restrict__ cube_r, const float* __restrict__ cube_o,
                       const float* __restrict__ W21, const float* __restrict__ W22,
                       const float* __restrict__ W23,
                       unsigned short* __restrict__ Wp1t, unsigned short* __restrict__ Wh1,
                       unsigned short* __restrict__ Wp3t, unsigned short* __restrict__ W22b,
                       unsigned short* __restrict__ W23b, unsigned short* __restrict__ Prt,
                       unsigned short* __restrict__ csb, unsigned short* __restrict__ crb,
                       unsigned short* __restrict__ cot)
{
    int i = blockIdx.x * 256 + threadIdx.x;
    if (i < 32768) { int d = i >> 6, s = i & 63; Wp1t[s * 512 + d] = f2bf(proj_s[i]); return; }
    i -= 32768;
    if (i < 32768) { Wh1[i] = f2bf(W21[i]); return; }
    i -= 32768;
    if (i < 32768) { int d = i >> 6, o = i & 63; Wp3t[o * 512 + d] = f2bf(proj_o[i]); return; }
    i -= 32768;
    if (i < 4096) { W22b[i] = f2bf(W22[i]); return; }
    i -= 4096;
    if (i < 4096) { W23b[i] = f2bf(W23[i]); return; }
    i -= 4096;
    if (i < 4096) { int k = i >> 6, n = i & 63; Prt[n * 64 + k] = f2bf(proj_r[i]); return; }
    i -= 4096;
    if (i < 262144) { csb[i] = f2bf(cube_s[i]); return; }   // [(s,y)][z]
    i -= 262144;
    if (i < 262144) { crb[i] = f2bf(cube_r[i]); return; }   // [(x,r)][z]
    i -= 262144;
    if (i < 262144) { int x = i >> 12, y = (i >> 6) & 63, o = i & 63;
                      cot[o * 4096 + x * 64 + y] = f2bf(cube_o[i]); return; }  // [o][(x,y)]
}

// ---------------------------------------------------------------------------
// K1: three [B,512]@[512,64] NT GEMMs. z=0: p1 ; z=1: h1 (bias+relu) ; z=2: p3
// ---------------------------------------------------------------------------
__global__ __launch_bounds__(256, 2) void k_proj(
    const float* __restrict__ in1, const float* __restrict__ in2, const float* __restrict__ in3,
    const unsigned short* __restrict__ Wp1t, const unsigned short* __restrict__ Wh1,
    const unsigned short* __restrict__ Wp3t, const float* __restrict__ b21,
    unsigned short* __restrict__ p1bf, unsigned short* __restrict__ hbf,
    unsigned short* __restrict__ p3bf)
{
    __shared__ __align__(16) unsigned short lds_w[64 * 512];   // weight [n][k] bf16, 64 KB
    __shared__ __align__(16) unsigned short lds_a[128 * 64];   // A chunk [row][k64] bf16, 16 KB
    const int z = blockIdx.y;
    const float* in = (z == 0) ? in1 : (z == 1) ? in2 : in3;
    const unsigned short* Wt = (z == 0) ? Wp1t : (z == 1) ? Wh1 : Wp3t;
    unsigned short* outp = (z == 0) ? p1bf : (z == 1) ? hbf : p3bf;

    const int t = threadIdx.x;
    const int b0 = blockIdx.x * 128;

    // stage full weight [64][512]
#pragma unroll
    for (int i = 0; i < 16; ++i) {
        int c = t + i * 256;
        int n = c >> 6, c16 = c & 63;
        uint4 v = *(const uint4*)(Wt + n * 512 + c16 * 8);
        *(uint4*)((char*)lds_w + swz(n * 1024 + c16 * 16, n)) = v;
    }
    const int wid = t >> 6, l = t & 63, lr = l & 15, lk = l >> 4;
    f32x4 acc[2][4] = {};
    for (int kc = 0; kc < 8; ++kc) {
        // stage A chunk: 128 rows x 64 k, f32 -> bf16
#pragma unroll
        for (int i = 0; i < 4; ++i) {
            int u = t + i * 256;
            int row = u >> 3, e8 = u & 7;
            const float* src = in + (size_t)(b0 + row) * ND + kc * 64 + e8 * 8;
            float4 fa = *(const float4*)src;
            float4 fb = *(const float4*)(src + 4);
            uint4 pk;
            pk.x = (unsigned)f2bf(fa.x) | ((unsigned)f2bf(fa.y) << 16);
            pk.y = (unsigned)f2bf(fa.z) | ((unsigned)f2bf(fa.w) << 16);
            pk.z = (unsigned)f2bf(fb.x) | ((unsigned)f2bf(fb.y) << 16);
            pk.w = (unsigned)f2bf(fb.z) | ((unsigned)f2bf(fb.w) << 16);
            *(uint4*)((char*)lds_a + swz(row * 128 + e8 * 16, row)) = pk;
        }
        __syncthreads();
#pragma unroll
        for (int ks = 0; ks < 2; ++ks) {
            short8 av[2], bv[4];
#pragma unroll
            for (int f = 0; f < 2; ++f) {
                int row = wid * 32 + f * 16 + lr;
                av[f] = *(const short8*)((const char*)lds_a + swz(row * 128 + (ks * 32 + lk * 8) * 2, row));
            }
#pragma unroll
            for (int g = 0; g < 4; ++g) {
                int n = g * 16 + lr;
                bv[g] = *(const short8*)((const char*)lds_w + swz(n * 1024 + (kc * 64 + ks * 32 + lk * 8) * 2, n));
            }
#pragma unroll
            for (int f = 0; f < 2; ++f)
#pragma unroll
                for (int g = 0; g < 4; ++g)
                    acc[f][g] = __builtin_amdgcn_mfma_f32_16x16x32_bf16(av[f], bv[g], acc[f][g], 0, 0, 0);
        }
        __syncthreads();
    }
    // epilogue
#pragma unroll
    for (int f = 0; f < 2; ++f)
#pragma unroll
        for (int g = 0; g < 4; ++g)
#pragma unroll
            for (int q = 0; q < 4; ++q) {
                int row = wid * 32 + f * 16 + lk * 4 + q;
                int col = g * 16 + lr;
                float v = acc[f][g][q];
                if (z == 1) v = fmaxf(v + b21[col], 0.0f);
                outp[(size_t)(b0 + row) * 64 + col] = f2bf(v);
            }
}

// ---------------------------------------------------------------------------
// K2: MLP tail, chained 64-wide NT GEMMs in LDS
// ---------------------------------------------------------------------------
DEV void mlp_stage(const unsigned short* src_lds, const unsigned short* w_lds,
                   const float* __restrict__ bias, bool do_relu,
                   unsigned short* dst_lds, unsigned short* __restrict__ dst_g,
                   int b0, int wid, int lr, int lk)
{
    f32x4 acc[2][4] = {};
#pragma unroll
    for (int ks = 0; ks < 2; ++ks) {
        short8 av[2], bv[4];
#pragma unroll
        for (int f = 0; f < 2; ++f) {
            int row = wid * 32 + f * 16 + lr;
            av[f] = *(const short8*)((const char*)src_lds + swz(row * 128 + (ks * 32 + lk * 8) * 2, row));
        }
#pragma unroll
        for (int g = 0; g < 4; ++g) {
            int n = g * 16 + lr;
            bv[g] = *(const short8*)((const char*)w_lds + swz(n * 128 + (ks * 32 + lk * 8) * 2, n));
        }
#pragma unroll
        for (int f = 0; f < 2; ++f)
#pragma unroll
            for (int g = 0; g < 4; ++g)
                acc[f][g] = __builtin_amdgcn_mfma_f32_16x16x32_bf16(av[f], bv[g], acc[f][g], 0, 0, 0);
    }
#pragma unroll
    for (int f = 0; f < 2; ++f)
#pragma unroll
        for (int g = 0; g < 4; ++g)
#pragma unroll
            for (int q = 0; q < 4; ++q) {
                int row = wid * 32 + f * 16 + lk * 4 + q;
                int col = g * 16 + lr;
                float v = acc[f][g][q];
                if (bias) v += bias[col];
                if (do_relu) v = fmaxf(v, 0.0f);
                unsigned short hv = f2bf(v);
                if (dst_lds) *(unsigned short*)((char*)dst_lds + swz(row * 128 + col * 2, row)) = hv;
                else dst_g[(size_t)(b0 + row) * 64 + col] = hv;
            }
}

__global__ __launch_bounds__(256, 2) void k_mlp(
    const unsigned short* __restrict__ hbf,
    const unsigned short* __restrict__ W22b, const unsigned short* __restrict__ W23b,
    const unsigned short* __restrict__ Prt,
    const float* __restrict__ b22, const float* __restrict__ b23,
    unsigned short* __restrict__ p2bf)
{
    __shared__ __align__(16) unsigned short lds_w[3][64 * 64];
    __shared__ __align__(16) unsigned short lds_x[128 * 64];
    __shared__ __align__(16) unsigned short lds_y[128 * 64];
    const int t = threadIdx.x;
    const int b0 = blockIdx.x * 128;
#pragma unroll
    for (int i = 0; i < 6; ++i) {
        int c = t + i * 256;
        int w = c >> 9, cc = c & 511;
        int n = cc >> 3, c16 = cc & 7;
        const unsigned short* W = (w == 0) ? W22b : (w == 1) ? W23b : Prt;
        uint4 v = *(const uint4*)(W + n * 64 + c16 * 8);
        *(uint4*)((char*)lds_w[w] + swz(n * 128 + c16 * 16, n)) = v;
    }
#pragma unroll
    for (int i = 0; i < 4; ++i) {
        int u = t + i * 256;
        int row = u >> 3, c16 = u & 7;
        uint4 v = *(const uint4*)(hbf + (size_t)(b0 + row) * 64 + c16 * 8);
        *(uint4*)((char*)lds_x + swz(row * 128 + c16 * 16, row)) = v;
    }
    __syncthreads();
    const int wid = t >> 6, l = t & 63, lr = l & 15, lk = l >> 4;
    mlp_stage(lds_x, lds_w[0], b22, true,  lds_y, nullptr, b0, wid, lr, lk);
    __syncthreads();
    mlp_stage(lds_y, lds_w[1], b23, false, lds_x, nullptr, b0, wid, lr, lk);
    __syncthreads();
    mlp_stage(lds_x, lds_w[2], nullptr, false, nullptr, p2bf, b0, wid, lr, lk);
}

// ---------------------------------------------------------------------------
// K3: F[(x,r)][(s,y)] = sum_z crb[(x,r),z] * csb[(s,y),z]   (NT, K=64)
// ---------------------------------------------------------------------------
__global__ __launch_bounds__(256, 2) void k_F(
    const unsigned short* __restrict__ crb, const unsigned short* __restrict__ csb,
    unsigned short* __restrict__ F2)
{
    __shared__ __align__(16) unsigned short lds_a[128 * 64];
    __shared__ __align__(16) unsigned short lds_b[128 * 64];
    const int t = threadIdx.x;
    const int m0 = blockIdx.x * 128, n0 = blockIdx.y * 128;
#pragma unroll
    for (int i = 0; i < 4; ++i) {
        int u = t + i * 256;
        int row = u >> 3, c16 = u & 7;
        uint4 va = *(const uint4*)(crb + (size_t)(m0 + row) * 64 + c16 * 8);
        *(uint4*)((char*)lds_a + swz(row * 128 + c16 * 16, row)) = va;
        uint4 vb = *(const uint4*)(csb + (size_t)(n0 + row) * 64 + c16 * 8);
        *(uint4*)((char*)lds_b + swz(row * 128 + c16 * 16, row)) = vb;
    }
    __syncthreads();
    const int wid = t >> 6, l = t & 63, lr = l & 15, lk = l >> 4;
    const int wm = wid & 1, wn = wid >> 1;
    f32x4 acc[4][4] = {};
#pragma unroll
    for (int ks = 0; ks < 2; ++ks) {
        short8 av[4], bv[4];
#pragma unroll
        for (int f = 0; f < 4; ++f) {
            int row = wm * 64 + f * 16 + lr;
            av[f] = *(const short8*)((const char*)lds_a + swz(row * 128 + (ks * 32 + lk * 8) * 2, row));
            int col = wn * 64 + f * 16 + lr;
            bv[f] = *(const short8*)((const char*)lds_b + swz(col * 128 + (ks * 32 + lk * 8) * 2, col));
        }
#pragma unroll
        for (int f = 0; f < 4; ++f)
#pragma unroll
            for (int g = 0; g < 4; ++g)
                acc[f][g] = __builtin_amdgcn_mfma_f32_16x16x32_bf16(av[f], bv[g], acc[f][g], 0, 0, 0);
    }
#pragma unroll
    for (int f = 0; f < 4; ++f)
#pragma unroll
        for (int g = 0; g < 4; ++g)
#pragma unroll
            for (int q = 0; q < 4; ++q) {
                int row = m0 + wm * 64 + f * 16 + lk * 4 + q;
                int col = n0 + wn * 64 + g * 16 + lr;
                F2[(size_t)row * 4096 + col] = f2bf(acc[f][g][q]);
            }
}

// ---------------------------------------------------------------------------
// K4: per-s: T_s[r,o] = sum_{x,y} F[x,r,s,y] * cot[o,(x,y)] -> Tts[s][(r,o)]
//     one workgroup per s; 4 waves split x (wave-local LDS slabs, no barriers)
// ---------------------------------------------------------------------------
__global__ __launch_bounds__(256, 1) void k_T(
    const unsigned short* __restrict__ F2, const unsigned short* __restrict__ cot,
    unsigned short* __restrict__ Tts)
{
    __shared__ __align__(16) unsigned short lds[4][2][64 * 64];   // per-wave A/B slabs, 64 KB
    const int s = blockIdx.x;
    const int t = threadIdx.x;
    const int wid = t >> 6, l = t & 63, lr = l & 15, lk = l >> 4;
    f32x4 acc[4][4] = {};
    for (int xi = 0; xi < 16; ++xi) {
        int x = wid * 16 + xi;
        // A slab: Aslab[r][y] = F2[(x*64+r)][(s*64+y)] ; B slab: Bslab[o][y] = cot[o][(x*64+y)]
#pragma unroll
        for (int i = 0; i < 8; ++i) {
            int u = l + i * 64;
            int rr = u >> 3, c16 = u & 7;
            uint4 va = *(const uint4*)(F2 + (size_t)(x * 64 + rr) * 4096 + s * 64 + c16 * 8);
            *(uint4*)((char*)lds[wid][0] + swz(rr * 128 + c16 * 16, rr)) = va;
            uint4 vb = *(const uint4*)(cot + (size_t)rr * 4096 + x * 64 + c16 * 8);
            *(uint4*)((char*)lds[wid][1] + swz(rr * 128 + c16 * 16, rr)) = vb;
        }
        asm volatile("s_waitcnt lgkmcnt(0)" ::: "memory");   // wave-local write->read fence
        __builtin_amdgcn_sched_barrier(0);                   // rule #18: pin reads below fence
#pragma unroll
        for (int ks = 0; ks < 2; ++ks) {
            short8 av[4], bv[4];
#pragma unroll
            for (int f = 0; f < 4; ++f) {
                int rr = f * 16 + lr;
                av[f] = *(const short8*)((const char*)lds[wid][0] + swz(rr * 128 + (ks * 32 + lk * 8) * 2, rr));
                bv[f] = *(const short8*)((const char*)lds[wid][1] + swz(rr * 128 + (ks * 32 + lk * 8) * 2, rr));
            }
#pragma unroll
            for (int f = 0; f < 4; ++f)
#pragma unroll
                for (int g = 0; g < 4; ++g)
                    acc[f][g] = __builtin_amdgcn_mfma_f32_16x16x32_bf16(av[f], bv[g], acc[f][g], 0, 0, 0);
        }
    }
    __syncthreads();
    // cross-wave reduction of partial T_s
    float* red = (float*)&lds[0][0][0];
#pragma unroll
    for (int f = 0; f < 4; ++f)
#pragma unroll
        for (int g = 0; g < 4; ++g)
#pragma unroll
            for (int q = 0; q < 4; ++q) {
                int r = f * 16 + lk * 4 + q;
                int o = g * 16 + lr;
                red[wid * 4096 + r * 64 + o] = acc[f][g][q];
            }
    __syncthreads();
#pragma unroll
    for (int i = 0; i < 16; ++i) {
        int idx = t + i * 256;
        float v = red[idx] + red[4096 + idx] + red[8192 + idx] + red[12288 + idx];
        Tts[(size_t)s * 4096 + idx] = f2bf(v);   // idx = r*64+o
    }
}

// ---------------------------------------------------------------------------
// K5: C[b,s] = sum_{k=(r,o)} (p2[b,r]*p3[b,o]) * Tts[s][k] ; out[b] += dot(p1[b,:], C[b,:])
//     A generated on the fly; k-chunk = 64 (one r per chunk); grid.y = k-split halves
// ---------------------------------------------------------------------------
__global__ __launch_bounds__(256, 2) void k_main(
    const unsigned short* __restrict__ p1bf, const unsigned short* __restrict__ p2bf,
    const unsigned short* __restrict__ p3bf, const unsigned short* __restrict__ Tts,
    float* __restrict__ out)
{
    __shared__ __align__(16) unsigned short lds_t[64 * 64];     // Tts chunk [s][k64]
    __shared__ __align__(16) unsigned short lds_p2[128 * 64];
    __shared__ __align__(16) unsigned short lds_p3[128 * 64];
    const int t = threadIdx.x;
    const int b0 = blockIdx.x * 128;
    const int kh = blockIdx.y;
#pragma unroll
    for (int i = 0; i < 4; ++i) {
        int u = t + i * 256;
        int row = u >> 3, c16 = u & 7;
        uint4 v2 = *(const uint4*)(p2bf + (size_t)(b0 + row) * 64 + c16 * 8);
        *(uint4*)((char*)lds_p2 + swz(row * 128 + c16 * 16, row)) = v2;
        uint4 v3 = *(const uint4*)(p3bf + (size_t)(b0 + row) * 64 + c16 * 8);
        *(uint4*)((char*)lds_p3 + swz(row * 128 + c16 * 16, row)) = v3;
    }
    __syncthreads();
    const int wid = t >> 6, l = t & 63, lr = l & 15, lk = l >> 4;
    // hoist p3 fragments to f32 registers (constant across k-chunks)
    float p3v[2][2][8];
#pragma unroll
    for (int f = 0; f < 2; ++f)
#pragma unroll
        for (int ks = 0; ks < 2; ++ks) {
            int row = wid * 32 + f * 16 + lr;
            short8 v = *(const short8*)((const char*)lds_p3 + swz(row * 128 + (ks * 32 + lk * 8) * 2, row));
#pragma unroll
            for (int j = 0; j < 8; ++j) p3v[f][ks][j] = bf2f((unsigned short)v[j]);
        }
    f32x4 acc[2][4] = {};
    for (int kc = kh * 32; kc < kh * 32 + 32; ++kc) {
#pragma unroll
        for (int i = 0; i < 2; ++i) {
            int u = t + i * 256;
            int srow = u >> 3, c16 = u & 7;
            uint4 v = *(const uint4*)(Tts + (size_t)srow * 4096 + kc * 64 + c16 * 8);
            *(uint4*)((char*)lds_t + swz(srow * 128 + c16 * 16, srow)) = v;
        }
        __syncthreads();
        float p2v[2];
#pragma unroll
        for (int f = 0; f < 2; ++f) {
            int row = wid * 32 + f * 16 + lr;
            p2v[f] = bf2f(*(const unsigned short*)((const char*)lds_p2 + swz(row * 128 + kc * 2, row)));
        }
#pragma unroll
        for (int ks = 0; ks < 2; ++ks) {
            short8 av[2], bv[4];
#pragma unroll
            for (int f = 0; f < 2; ++f) {
                short8 a;
#pragma unroll
                for (int j = 0; j < 8; ++j) a[j] = (short)f2bf(p2v[f] * p3v[f][ks][j]);
                av[f] = a;
            }
#pragma unroll
            for (int g = 0; g < 4; ++g) {
                int n = g * 16 + lr;
                bv[g] = *(const short8*)((const char*)lds_t + swz(n * 128 + (ks * 32 + lk * 8) * 2, n));
            }
#pragma unroll
            for (int f = 0; f < 2; ++f)
#pragma unroll
                for (int g = 0; g < 4; ++g)
                    acc[f][g] = __builtin_amdgcn_mfma_f32_16x16x32_bf16(av[f], bv[g], acc[f][g], 0, 0, 0);
        }
        __syncthreads();
    }
    // epilogue: out[b] += sum_s C[b,s] * p1[b,s]
    float rsum[2][4] = {};
#pragma unroll
    for (int f = 0; f < 2; ++f)
#pragma unroll
        for (int g = 0; g < 4; ++g)
#pragma unroll
            for (int q = 0; q < 4; ++q) {
                int row = wid * 32 + f * 16 + lk * 4 + q;
                int col = g * 16 + lr;
                float p1v = bf2f(p1bf[(size_t)(b0 + row) * 64 + col]);
                rsum[f][q] += acc[f][g][q] * p1v;
            }
#pragma unroll
    for (int f = 0; f < 2; ++f)
#pragma unroll
        for (int q = 0; q < 4; ++q) {
            float v = rsum[f][q];
            v += __shfl_xor(v, 1);
            v += __shfl_xor(v, 2);
            v += __shfl_xor(v, 4);
            v += __shfl_xor(v, 8);
            if (lr == 0) {
                int row = wid * 32 + f * 16 + lk * 4 + q;
                atomicAdd(&out[b0 + row], v);
            }
        }
}

// ---------------------------------------------------------------------------
extern "C" void kernel_launch(void* const* d_in, const int* in_sizes, int n_in,
                              void* d_out, int out_size, void* d_ws, size_t ws_size,
                              hipStream_t stream)
{
    const float* in1    = (const float*)d_in[0];
    const float* in2    = (const float*)d_in[1];
    const float* in3    = (const float*)d_in[2];
    const float* proj_s = (const float*)d_in[3];
    const float* proj_r = (const float*)d_in[4];
    const float* proj_o = (const float*)d_in[5];
    const float* cube_s = (const float*)d_in[6];
    const float* cube_r = (const float*)d_in[7];
    const float* cube_o = (const float*)d_in[8];
    const float* W21    = (const float*)d_in[9];
    const float* b21    = (const float*)d_in[10];
    const float* W22    = (const float*)d_in[11];
    const float* b22    = (const float*)d_in[12];
    const float* W23    = (const float*)d_in[13];
    const float* b23    = (const float*)d_in[14];
    float* out = (float*)d_out;

    char* ws = (char*)d_ws;
    size_t off = 0;
    auto alloc = [&](size_t bytes) -> char* {
        char* p = ws + off;
        off += (bytes + 255) & ~(size_t)255;
        return p;
    };
    unsigned short* p1bf = (unsigned short*)alloc((size_t)NB * 64 * 2);   // 2 MB
    unsigned short* hbf  = (unsigned short*)alloc((size_t)NB * 64 * 2);
    unsigned short* p2bf = (unsigned short*)alloc((size_t)NB * 64 * 2);
    unsigned short* p3bf = (unsigned short*)alloc((size_t)NB * 64 * 2);
    unsigned short* Wp1t = (unsigned short*)alloc(64 * 512 * 2);
    unsigned short* Wh1  = (unsigned short*)alloc(64 * 512 * 2);
    unsigned short* Wp3t = (unsigned short*)alloc(64 * 512 * 2);
    unsigned short* W22b = (unsigned short*)alloc(64 * 64 * 2);
    unsigned short* W23b = (unsigned short*)alloc(64 * 64 * 2);
    unsigned short* Prt  = (unsigned short*)alloc(64 * 64 * 2);
    unsigned short* csb  = (unsigned short*)alloc(262144 * 2);
    unsigned short* crb  = (unsigned short*)alloc(262144 * 2);
    unsigned short* cot  = (unsigned short*)alloc(262144 * 2);
    unsigned short* Tts  = (unsigned short*)alloc(64 * 4096 * 2);
    unsigned short* F2   = (unsigned short*)alloc((size_t)4096 * 4096 * 2); // 32 MB

    hipMemsetAsync(d_out, 0, (size_t)out_size * sizeof(float), stream);

    k_prep<<<3504, 256, 0, stream>>>(proj_s, proj_r, proj_o, cube_s, cube_r, cube_o,
                                     W21, W22, W23,
                                     Wp1t, Wh1, Wp3t, W22b, W23b, Prt, csb, crb, cot);
    k_proj<<<dim3(NB / 128, 3), 256, 0, stream>>>(in1, in2, in3, Wp1t, Wh1, Wp3t, b21,
                                                  p1bf, hbf, p3bf);
    k_mlp<<<NB / 128, 256, 0, stream>>>(hbf, W22b, W23b, Prt, b22, b23, p2bf);
    k_F<<<dim3(32, 32), 256, 0, stream>>>(crb, csb, F2);
    k_T<<<64, 256, 0, stream>>>(F2, cot, Tts);
    k_main<<<dim3(NB / 128, 2), 256, 0, stream>>>(p1bf, p2bf, p3bf, Tts, out);
}

// Round 4
// 228.900 us; speedup vs baseline: 1.0312x; 1.0312x over previous
//
#include <hip/hip_runtime.h>
#include <hip/hip_bf16.h>
#include <cstdint>
#include <cstddef>

// ---------------------------------------------------------------------------
// TriangleTensorNetwork, restructured:
//   T[s,r,o] = sum_{x,y,z} cs[s,y,z] cr[x,r,z] co[x,y,o]   (batch-independent)
//   out[b]   = sum_s p1[b,s] * sum_{r,o} p2[b,r] p3[b,o] T[s,r,o]
// Round-4: R3 structure with defensive sync (R3 failed at absmax 3.6; prime
// suspect: wave-fence waited lgkmcnt only — flat_store to LDS needs vmcnt too;
// __syncthreads drains both).  All packing pure C (m240: compiler emits
// v_cvt_pk itself).  k_main k-split x4 for occupancy.
//   k_prep : weight transposes/casts (bf16 [n][k] layouts) + cot transpose
//   k_F    : F[(x r)][(s y)] = sum_z cr*cs   (4096x4096, K=64, no LDS)
//   k_proj : p1,p3 projections + h1->MLP chain->p2 (z==1 fused, barrier'd)
//   k_T    : Tf[s][(r o)] += sum_{x in xh} F co  (grid (64,4), f32 atomics)
//   k_cast : Tf f32 -> Tts bf16 [kc][s][kloc]
//   k_main : C[b,s]=sum_k (p2*p3) Tts ; out[b]=dot(p1,C)  (dbuf LDS chunks)
// ---------------------------------------------------------------------------

typedef __attribute__((ext_vector_type(8))) short short8;
typedef __attribute__((ext_vector_type(4))) float f32x4;

#define DEV static __device__ __forceinline__

constexpr int NB = 16384;   // batch
constexpr int ND = 512;     // outer dim

DEV unsigned short f2bf(float f) {
    union { float f; unsigned u; } v; v.f = f;
    unsigned r = v.u + 0x7FFFu + ((v.u >> 16) & 1u);   // RNE
    return (unsigned short)(r >> 16);
}
DEV float bf2f(unsigned short h) {
    union { unsigned u; float f; } v; v.u = ((unsigned)h) << 16;
    return v.f;
}
DEV unsigned pack2(float lo, float hi) {
    return (unsigned)f2bf(lo) | ((unsigned)f2bf(hi) << 16);
}
// load 8 contiguous f32, convert to bf16x8 fragment in regs
DEV short8 ldA_f32(const float* p) {
    float4 a = *(const float4*)p, b = *(const float4*)(p + 4);
    union { unsigned u[4]; short8 s; } v;
    v.u[0] = pack2(a.x, a.y); v.u[1] = pack2(a.z, a.w);
    v.u[2] = pack2(b.x, b.y); v.u[3] = pack2(b.z, b.w);
    return v.s;
}

// ---------------------------------------------------------------------------
// K0: weight prep
// ---------------------------------------------------------------------------
__global__ void k_prep(const float* __restrict__ proj_s, const float* __restrict__ proj_r,
                       const float* __restrict__ proj_o, const float* __restrict__ cube_o,
                       const float* __restrict__ W21, const float* __restrict__ W22,
                       const float* __restrict__ W23,
                       unsigned short* __restrict__ Wp1t, unsigned short* __restrict__ Wh1,
                       unsigned short* __restrict__ Wp3t, unsigned short* __restrict__ W22b,
                       unsigned short* __restrict__ W23b, unsigned short* __restrict__ Prt,
                       unsigned short* __restrict__ cot)
{
    int i = blockIdx.x * 256 + threadIdx.x;
    if (i < 32768) { int d = i >> 6, s = i & 63; Wp1t[s * 512 + d] = f2bf(proj_s[i]); return; }
    i -= 32768;
    if (i < 32768) { Wh1[i] = f2bf(W21[i]); return; }
    i -= 32768;
    if (i < 32768) { int d = i >> 6, o = i & 63; Wp3t[o * 512 + d] = f2bf(proj_o[i]); return; }
    i -= 32768;
    if (i < 4096) { W22b[i] = f2bf(W22[i]); return; }
    i -= 4096;
    if (i < 4096) { W23b[i] = f2bf(W23[i]); return; }
    i -= 4096;
    if (i < 4096) { int k = i >> 6, n = i & 63; Prt[n * 64 + k] = f2bf(proj_r[i]); return; }
    i -= 4096;
    if (i < 262144) { int x = i >> 12, y = (i >> 6) & 63, o = i & 63;
                      cot[o * 4096 + x * 64 + y] = f2bf(cube_o[i]); return; }  // [o][(x,y)]
}

// ---------------------------------------------------------------------------
// K_F: F[(x r)][(s y)] = sum_z cr[(x r),z] * cs[(s y),z]  -- no LDS, no barrier
// ---------------------------------------------------------------------------
__global__ __launch_bounds__(256, 2) void k_F(
    const float* __restrict__ cr, const float* __restrict__ cs,
    unsigned short* __restrict__ F2)
{
    const int t = threadIdx.x, wid = t >> 6, l = t & 63, lr = l & 15, lk = l >> 4;
    const int wm = wid & 1, wn = wid >> 1;
    const int m0 = blockIdx.x * 128 + wm * 64, n0 = blockIdx.y * 128 + wn * 64;
    f32x4 acc[4][4] = {};
#pragma unroll
    for (int ks = 0; ks < 2; ++ks) {
        short8 av[4], bv[4];
#pragma unroll
        for (int f = 0; f < 4; ++f) {
            av[f] = ldA_f32(cr + (size_t)(m0 + f * 16 + lr) * 64 + ks * 32 + lk * 8);
            bv[f] = ldA_f32(cs + (size_t)(n0 + f * 16 + lr) * 64 + ks * 32 + lk * 8);
        }
#pragma unroll
        for (int f = 0; f < 4; ++f)
#pragma unroll
            for (int g = 0; g < 4; ++g)
                acc[f][g] = __builtin_amdgcn_mfma_f32_16x16x32_bf16(av[f], bv[g], acc[f][g], 0, 0, 0);
    }
#pragma unroll
    for (int f = 0; f < 4; ++f)
#pragma unroll
        for (int g = 0; g < 4; ++g)
#pragma unroll
            for (int q = 0; q < 4; ++q)
                F2[(size_t)(m0 + f * 16 + lk * 4 + q) * 4096 + n0 + g * 16 + lr] = f2bf(acc[f][g][q]);
}

// ---------------------------------------------------------------------------
// K_proj: z=0: p1 ; z=2: p3 ; z=1: h1 + fused 3-stage MLP -> p2
//   wave = 16 rows; per-wave LDS slab; __syncthreads() between MLP stages
// ---------------------------------------------------------------------------
DEV void mlp_mm(const unsigned short* slab_w, const unsigned short* __restrict__ W,
                int lr, int lk, f32x4 acc[4])
{
#pragma unroll
    for (int ks = 0; ks < 2; ++ks) {
        short8 av = *(const short8*)((const char*)slab_w +
                      (lr * 128 + ((ks * 64 + lk * 16) ^ ((lr & 7) << 4))));
#pragma unroll
        for (int g = 0; g < 4; ++g) {
            short8 bv = *(const short8*)(W + (g * 16 + lr) * 64 + ks * 32 + lk * 8);
            acc[g] = __builtin_amdgcn_mfma_f32_16x16x32_bf16(av, bv, acc[g], 0, 0, 0);
        }
    }
}
DEV void store_slab(unsigned short* slab_w, int lr, int lk, const f32x4 acc[4],
                    const float* __restrict__ bias, bool relu_)
{
#pragma unroll
    for (int g = 0; g < 4; ++g) {
        float bcol = bias ? bias[g * 16 + lr] : 0.0f;
#pragma unroll
        for (int q = 0; q < 4; ++q) {
            int r = lk * 4 + q, c = g * 16 + lr;
            float v = acc[g][q] + bcol;
            if (relu_) v = fmaxf(v, 0.0f);
            *(unsigned short*)((char*)slab_w + (r * 128 + ((c * 2) ^ ((r & 7) << 4)))) = f2bf(v);
        }
    }
}

__global__ __launch_bounds__(256, 2) void k_proj(
    const float* __restrict__ in1, const float* __restrict__ in2, const float* __restrict__ in3,
    const unsigned short* __restrict__ Wp1t, const unsigned short* __restrict__ Wh1,
    const unsigned short* __restrict__ Wp3t,
    const unsigned short* __restrict__ W22b, const unsigned short* __restrict__ W23b,
    const unsigned short* __restrict__ Prt,
    const float* __restrict__ b21, const float* __restrict__ b22, const float* __restrict__ b23,
    unsigned short* __restrict__ p1bf, unsigned short* __restrict__ p2bf,
    unsigned short* __restrict__ p3bf)
{
    __shared__ __align__(16) unsigned short slab[4][1024];   // per-wave 16x64 bf16
    const int z = blockIdx.y;
    const float* in = (z == 0) ? in1 : (z == 1) ? in2 : in3;
    const unsigned short* Wt = (z == 0) ? Wp1t : (z == 1) ? Wh1 : Wp3t;
    const int t = threadIdx.x, wid = t >> 6, l = t & 63, lr = l & 15, lk = l >> 4;
    const int rbase = blockIdx.x * 64 + wid * 16;
    const float* arow = in + (size_t)(rbase + lr) * ND;

    f32x4 acc[4] = {};
#pragma unroll
    for (int kc = 0; kc < 8; ++kc) {
#pragma unroll
        for (int ks = 0; ks < 2; ++ks) {
            short8 av = ldA_f32(arow + kc * 64 + ks * 32 + lk * 8);
#pragma unroll
            for (int g = 0; g < 4; ++g) {
                short8 bv = *(const short8*)(Wt + (size_t)(g * 16 + lr) * 512 + kc * 64 + ks * 32 + lk * 8);
                acc[g] = __builtin_amdgcn_mfma_f32_16x16x32_bf16(av, bv, acc[g], 0, 0, 0);
            }
        }
    }
    if (z != 1) {
        unsigned short* outp = (z == 0) ? p1bf : p3bf;
#pragma unroll
        for (int g = 0; g < 4; ++g)
#pragma unroll
            for (int q = 0; q < 4; ++q)
                outp[(size_t)(rbase + lk * 4 + q) * 64 + g * 16 + lr] = f2bf(acc[g][q]);
    } else {
        unsigned short* slw = slab[wid];
        store_slab(slw, lr, lk, acc, b21, true);        // h1 = relu(.+b21)
        __syncthreads();                                // full drain (vm+lgkm)
        f32x4 a2[4] = {}; mlp_mm(slw, W22b, lr, lk, a2);
        store_slab(slw, lr, lk, a2, b22, true);         // h2 = relu(.+b22)
        __syncthreads();
        f32x4 a3[4] = {}; mlp_mm(slw, W23b, lr, lk, a3);
        store_slab(slw, lr, lk, a3, b23, false);        // h3 = .+b23
        __syncthreads();
        f32x4 a4[4] = {}; mlp_mm(slw, Prt, lr, lk, a4); // p2 = h3 @ proj_r
#pragma unroll
        for (int g = 0; g < 4; ++g)
#pragma unroll
            for (int q = 0; q < 4; ++q)
                p2bf[(size_t)(rbase + lk * 4 + q) * 64 + g * 16 + lr] = f2bf(a4[g][q]);
    }
}

// ---------------------------------------------------------------------------
// K_T: Tf[s][(r o)] += sum_{x in xh-quarter} F[(x r)][s-slice y] * cot[o][(x y)]
//   grid (64 s, 4 xh); direct global frags; LDS only for final 4-wave reduce
// ---------------------------------------------------------------------------
__global__ __launch_bounds__(256, 2) void k_T(
    const unsigned short* __restrict__ F2, const unsigned short* __restrict__ cot,
    float* __restrict__ Tf)
{
    __shared__ float red[4][4096];
    const int s = blockIdx.x, xh = blockIdx.y;
    const int t = threadIdx.x, wid = t >> 6, l = t & 63, lr = l & 15, lk = l >> 4;
    f32x4 acc[4][4] = {};
#pragma unroll
    for (int xi = 0; xi < 4; ++xi) {
        int x = xh * 16 + wid * 4 + xi;
#pragma unroll
        for (int ks = 0; ks < 2; ++ks) {
            short8 av[4], bv[4];
#pragma unroll
            for (int f = 0; f < 4; ++f) {
                av[f] = *(const short8*)(F2 + (size_t)(x * 64 + f * 16 + lr) * 4096 + s * 64 + ks * 32 + lk * 8);
                bv[f] = *(const short8*)(cot + (size_t)(f * 16 + lr) * 4096 + x * 64 + ks * 32 + lk * 8);
            }
#pragma unroll
            for (int f = 0; f < 4; ++f)
#pragma unroll
                for (int g = 0; g < 4; ++g)
                    acc[f][g] = __builtin_amdgcn_mfma_f32_16x16x32_bf16(av[f], bv[g], acc[f][g], 0, 0, 0);
        }
    }
#pragma unroll
    for (int f = 0; f < 4; ++f)
#pragma unroll
        for (int g = 0; g < 4; ++g)
#pragma unroll
            for (int q = 0; q < 4; ++q)
                red[wid][(f * 16 + lk * 4 + q) * 64 + g * 16 + lr] = acc[f][g][q];
    __syncthreads();
#pragma unroll
    for (int i = 0; i < 16; ++i) {
        int idx = t + i * 256;
        atomicAdd(&Tf[(size_t)s * 4096 + idx],
                  red[0][idx] + red[1][idx] + red[2][idx] + red[3][idx]);
    }
}

// ---------------------------------------------------------------------------
// K_cast: Tf f32 [s][4096] -> Tts bf16 chunked [kc][s][kloc]
// ---------------------------------------------------------------------------
__global__ void k_cast(const float* __restrict__ Tf, unsigned short* __restrict__ Tts)
{
    int i = blockIdx.x * 256 + threadIdx.x;
#pragma unroll
    for (int j = 0; j < 4; ++j) {
        int e = i * 4 + j;                 // e = s*4096 + k
        int s = e >> 12, k = e & 4095;
        int kc = k >> 6, kloc = k & 63;
        Tts[kc * 4096 + s * 64 + kloc] = f2bf(Tf[e]);
    }
}

// ---------------------------------------------------------------------------
// K_main: C[b,s] = sum_k (p2[b,r]*p3[b,o]) Tts[s][k] ; out[b] += dot(p1[b],C[b])
//   64-row blocks, grid (256, 4 kh); dbuf LDS chunk (swizzled), 1 barrier/kc
// ---------------------------------------------------------------------------
__global__ __launch_bounds__(256, 4) void k_main(
    const unsigned short* __restrict__ p1bf, const unsigned short* __restrict__ p2bf,
    const unsigned short* __restrict__ p3bf, const unsigned short* __restrict__ Tts,
    float* __restrict__ out)
{
    __shared__ __align__(16) unsigned short tb[2][4096];   // two 8KB chunks [s][k64] swizzled
    const int t = threadIdx.x, wid = t >> 6, l = t & 63, lr = l & 15, lk = l >> 4;
    const int b0 = blockIdx.x * 64, kh = blockIdx.y;       // kh in [0,4): 16 chunks each
    const int row = b0 + wid * 16 + lr;

    // p3 fragment values (f32) and p2 quarter-row (bf16x8 regs)
    float p3v[2][8];
#pragma unroll
    for (int ks = 0; ks < 2; ++ks) {
        short8 v = *(const short8*)(p3bf + (size_t)row * 64 + ks * 32 + lk * 8);
#pragma unroll
        for (int j = 0; j < 8; ++j) p3v[ks][j] = bf2f((unsigned short)v[j]);
    }
    short8 p2r[2];
#pragma unroll
    for (int i = 0; i < 2; ++i)
        p2r[i] = *(const short8*)(p2bf + (size_t)row * 64 + kh * 16 + i * 8);

    // staging geometry: thread covers bytes [t*32, t*32+32) of the 8KB chunk
    const int srow_st = t >> 2, kb_st = (t & 3) * 32;
    const unsigned swz0 = (unsigned)(kb_st ^ ((srow_st & 7) << 4));
    const unsigned swz1 = (unsigned)((kb_st + 16) ^ ((srow_st & 7) << 4));

    // prologue: stage chunk 0
    {
        const uint4* src = (const uint4*)((const char*)(Tts + (size_t)(kh * 16) * 4096) + t * 32);
        uint4 v0 = src[0], v1 = src[1];
        char* dst = (char*)tb[0] + srow_st * 128;
        *(uint4*)(dst + swz0) = v0;
        *(uint4*)(dst + swz1) = v1;
        __syncthreads();
    }

    f32x4 acc[4] = {};
#pragma unroll
    for (int i = 0; i < 16; ++i) {
        const int buf = i & 1;
        // 1) issue next-chunk loads early (hide HBM/L2 latency under MFMA)
        uint4 n0 = {}, n1 = {};
        if (i < 15) {
            const uint4* src = (const uint4*)((const char*)(Tts + (size_t)(kh * 16 + i + 1) * 4096) + t * 32);
            n0 = src[0]; n1 = src[1];
        }
        // 2) compute current chunk
        float p2s = bf2f((unsigned short)p2r[i >> 3][i & 7]);
#pragma unroll
        for (int ks = 0; ks < 2; ++ks) {
            union { unsigned u[4]; short8 s; } a;
#pragma unroll
            for (int jj = 0; jj < 4; ++jj)
                a.u[jj] = pack2(p2s * p3v[ks][jj * 2], p2s * p3v[ks][jj * 2 + 1]);
#pragma unroll
            for (int g = 0; g < 4; ++g) {
                int n = g * 16 + lr;
                short8 bv = *(const short8*)((const char*)tb[buf] +
                              (n * 128 + ((ks * 64 + lk * 16) ^ ((n & 7) << 4))));
                acc[g] = __builtin_amdgcn_mfma_f32_16x16x32_bf16(a.s, bv, acc[g], 0, 0, 0);
            }
        }
        // 3) write next chunk into other buffer, one barrier per iteration
        if (i < 15) {
            char* dst = (char*)tb[buf ^ 1] + srow_st * 128;
            *(uint4*)(dst + swz0) = n0;
            *(uint4*)(dst + swz1) = n1;
            __syncthreads();
        }
    }

    // epilogue: out[b] += sum_s C[b,s] * p1[b,s]
    float rsum[4] = {};
#pragma unroll
    for (int g = 0; g < 4; ++g)
#pragma unroll
        for (int q = 0; q < 4; ++q) {
            int r = b0 + wid * 16 + lk * 4 + q, c = g * 16 + lr;
            rsum[q] += acc[g][q] * bf2f(p1bf[(size_t)r * 64 + c]);
        }
#pragma unroll
    for (int q = 0; q < 4; ++q) {
        float v = rsum[q];
        v += __shfl_xor(v, 1);
        v += __shfl_xor(v, 2);
        v += __shfl_xor(v, 4);
        v += __shfl_xor(v, 8);
        if (lr == 0)
            atomicAdd(&out[b0 + wid * 16 + lk * 4 + q], v);
    }
}

// ---------------------------------------------------------------------------
extern "C" void kernel_launch(void* const* d_in, const int* in_sizes, int n_in,
                              void* d_out, int out_size, void* d_ws, size_t ws_size,
                              hipStream_t stream)
{
    const float* in1    = (const float*)d_in[0];
    const float* in2    = (const float*)d_in[1];
    const float* in3    = (const float*)d_in[2];
    const float* proj_s = (const float*)d_in[3];
    const float* proj_r = (const float*)d_in[4];
    const float* proj_o = (const float*)d_in[5];
    const float* cube_s = (const float*)d_in[6];
    const float* cube_r = (const float*)d_in[7];
    const float* cube_o = (const float*)d_in[8];
    const float* W21    = (const float*)d_in[9];
    const float* b21    = (const float*)d_in[10];
    const float* W22    = (const float*)d_in[11];
    const float* b22    = (const float*)d_in[12];
    const float* W23    = (const float*)d_in[13];
    const float* b23    = (const float*)d_in[14];
    float* out = (float*)d_out;

    char* ws = (char*)d_ws;
    size_t off = 0;
    auto alloc = [&](size_t bytes) -> char* {
        char* p = ws + off;
        off += (bytes + 255) & ~(size_t)255;
        return p;
    };
    unsigned short* p1bf = (unsigned short*)alloc((size_t)NB * 64 * 2);
    unsigned short* p2bf = (unsigned short*)alloc((size_t)NB * 64 * 2);
    unsigned short* p3bf = (unsigned short*)alloc((size_t)NB * 64 * 2);
    unsigned short* Wp1t = (unsigned short*)alloc(64 * 512 * 2);
    unsigned short* Wh1  = (unsigned short*)alloc(64 * 512 * 2);
    unsigned short* Wp3t = (unsigned short*)alloc(64 * 512 * 2);
    unsigned short* W22b = (unsigned short*)alloc(64 * 64 * 2);
    unsigned short* W23b = (unsigned short*)alloc(64 * 64 * 2);
    unsigned short* Prt  = (unsigned short*)alloc(64 * 64 * 2);
    unsigned short* cot  = (unsigned short*)alloc(262144 * 2);
    float*          Tf   = (float*)alloc(262144 * 4);            // 1 MB f32
    unsigned short* Tts  = (unsigned short*)alloc(262144 * 2);
    unsigned short* F2   = (unsigned short*)alloc((size_t)4096 * 4096 * 2); // 32 MB

    hipMemsetAsync(d_out, 0, (size_t)out_size * sizeof(float), stream);
    hipMemsetAsync(Tf, 0, 262144 * sizeof(float), stream);

    k_prep<<<1456, 256, 0, stream>>>(proj_s, proj_r, proj_o, cube_o, W21, W22, W23,
                                     Wp1t, Wh1, Wp3t, W22b, W23b, Prt, cot);
    k_F<<<dim3(32, 32), 256, 0, stream>>>(cube_r, cube_s, F2);
    k_proj<<<dim3(NB / 64, 3), 256, 0, stream>>>(in1, in2, in3, Wp1t, Wh1, Wp3t,
                                                 W22b, W23b, Prt, b21, b22, b23,
                                                 p1bf, p2bf, p3bf);
    k_T<<<dim3(64, 4), 256, 0, stream>>>(F2, cot, Tf);
    k_cast<<<256, 256, 0, stream>>>(Tf, Tts);
    k_main<<<dim3(NB / 64, 4), 256, 0, stream>>>(p1bf, p2bf, p3bf, Tts, out);
}